// Round 8
// baseline (195.478 us; speedup 1.0000x reference)
//
#include <hip/hip_runtime.h>
#include <hip/hip_bf16.h>
#include <stdint.h>
#include <stddef.h>

#define SEQ  8192
#define DIN  1024
#define DOUT 1024

typedef __hip_bfloat16 bf16;
typedef short bf16x8 __attribute__((ext_vector_type(8)));   // 8 bf16 = 4 VGPRs
typedef float f32x4  __attribute__((ext_vector_type(4)));

// async global->LDS, 16B per lane; dest = wave-uniform base + lane*16
#define GLOAD_LDS16(gptr, lptr)                                                     \
  __builtin_amdgcn_global_load_lds(                                                 \
      (const __attribute__((address_space(1))) void*)(gptr),                        \
      (__attribute__((address_space(3))) void*)(lptr), 16, 0, 0)

__device__ inline void store_out(float* p, float v) { *p = v; }
__device__ inline void store_out(bf16* p, float v) { *p = __float2bfloat16(v); }
__device__ inline short bfbits(float f) { bf16 b = __float2bfloat16(f); return *(short*)&b; }

__device__ inline bf16x8 cvt8(const float4& a, const float4& b) {
  bf16x8 o;
  o[0] = bfbits(a.x); o[1] = bfbits(a.y); o[2] = bfbits(a.z); o[3] = bfbits(a.w);
  o[4] = bfbits(b.x); o[5] = bfbits(b.y); o[6] = bfbits(b.z); o[7] = bfbits(b.w);
  return o;
}

// ---------------------------------------------------------------------------
// 128x128 tile, BK=64, XOR-swizzled LDS, double-buffered (R4-proven form).
// As/Bs each 2 x 128*64 bf16 -> 64 KB total. ATOMIC: atomicAdd fp32 epilogue.
template <typename OutT, bool ATOMIC>
__device__ __forceinline__ void gemm128_body(
    const bf16* __restrict__ A, const bf16* __restrict__ B, OutT* __restrict__ C,
    int bx, int by, int K, int lda, int ldb, int ldc, bf16* As, bf16* Bs)
{
  const int lane = threadIdx.x & 63;
  const int wave = threadIdx.x >> 6;
  const int m0 = by * 128, n0 = bx * 128;

  const int sR = lane >> 3;
  const int sC = (lane & 7) ^ sR;       // XOR swizzle -> conflict-free b128 reads
  const bf16* gA = A + (size_t)(m0 + sR) * lda + sC * 8;
  const bf16* gB = B + (size_t)(n0 + sR) * ldb + sC * 8;

  f32x4 acc[4][4];
#pragma unroll
  for (int i = 0; i < 4; ++i)
#pragma unroll
    for (int j = 0; j < 4; ++j)
      acc[i][j] = (f32x4){0.f, 0.f, 0.f, 0.f};

  const int wr = wave >> 1, wc = wave & 1;
  const int mW = wr * 64, nW = wc * 64;
  const int fragRow = lane & 15;
  const int quad = lane >> 4;

  auto stage = [&](int kt, int buf) {
    bf16* dA = As + buf * (128 * 64);
    bf16* dB = Bs + buf * (128 * 64);
#pragma unroll
    for (int t = 0; t < 4; ++t) {
      const int R = (t * 4 + wave) * 8;
      GLOAD_LDS16(gA + (size_t)R * lda + kt, &dA[R * 64]);
      GLOAD_LDS16(gB + (size_t)R * ldb + kt, &dB[R * 64]);
    }
  };

  const int nT = K >> 6;
  stage(0, 0);
  for (int kt = 0; kt < nT; ++kt) {
    const int buf = kt & 1;
    if (kt + 1 < nT) {
      stage((kt + 1) << 6, buf ^ 1);
      asm volatile("s_waitcnt vmcnt(8)" ::: "memory");   // tile kt complete
    } else {
      asm volatile("s_waitcnt vmcnt(0)" ::: "memory");
    }
    asm volatile("s_barrier" ::: "memory");

    const bf16* Ab = As + buf * (128 * 64);
    const bf16* Bb = Bs + buf * (128 * 64);
    bf16x8 afr[2][4], bfr[2][4];
#pragma unroll
    for (int s = 0; s < 2; ++s) {
      const int cw = s * 4 + quad;
#pragma unroll
      for (int i = 0; i < 4; ++i) {
        const int ra = mW + i * 16 + fragRow;
        afr[s][i] = *(const bf16x8*)&Ab[ra * 64 + ((cw ^ (ra & 7)) << 3)];
        const int rb = nW + i * 16 + fragRow;
        bfr[s][i] = *(const bf16x8*)&Bb[rb * 64 + ((cw ^ (rb & 7)) << 3)];
      }
    }
    asm volatile("s_waitcnt lgkmcnt(0)" ::: "memory");
    asm volatile("s_barrier" ::: "memory");

#pragma unroll
    for (int s = 0; s < 2; ++s)
#pragma unroll
      for (int i = 0; i < 4; ++i)
#pragma unroll
        for (int j = 0; j < 4; ++j)
          acc[i][j] = __builtin_amdgcn_mfma_f32_16x16x32_bf16(afr[s][i], bfr[s][j], acc[i][j], 0, 0, 0);
  }

  const int cCol  = lane & 15;
  const int cRow4 = quad * 4;
#pragma unroll
  for (int i = 0; i < 4; ++i)
#pragma unroll
    for (int j = 0; j < 4; ++j) {
      const int row = m0 + mW + i * 16 + cRow4;
      const int col = n0 + nW + j * 16 + cCol;
#pragma unroll
      for (int r = 0; r < 4; ++r) {
        if (ATOMIC)
          atomicAdd((float*)&C[(size_t)(row + r) * ldc + col], acc[i][j][r]);
        else
          store_out(&C[(size_t)(row + r) * ldc + col], acc[i][j][r]);
      }
    }
}

// ---------------------------------------------------------------------------
// 64x64 tile, BK=64, double-buffered. Operands independently bf16-DMA or
// fp32 with cvt-in-staging (float4 loads -> bf16x8 -> swizzled ds_write_b128).
// One barrier per iter; vmcnt(0) drain per iter (smalls are latency-tolerant).
template <bool AF32, bool BF32, typename OutT>
__device__ __forceinline__ void gemm64s_body(
    const void* __restrict__ Av, const void* __restrict__ Bv, OutT* __restrict__ C,
    int bx, int by, int K, int lda, int ldb, int ldc, bf16* As, bf16* Bs)
{
  const int tid  = threadIdx.x;
  const int lane = tid & 63;
  const int wave = tid >> 6;
  const int m0 = by * 64, n0 = bx * 64;

  // DMA addressing (bf16 operand)
  const int sR = lane >> 3;
  const int sC = (lane & 7) ^ sR;
  const bf16* gA16 = AF32 ? nullptr : (const bf16*)Av + (size_t)(m0 + sR) * lda + sC * 8;
  const bf16* gB16 = BF32 ? nullptr : (const bf16*)Bv + (size_t)(n0 + sR) * ldb + sC * 8;
  // cvt addressing (fp32 operand): thread -> row r=tid>>2, cols qd*16..+15
  const int cR = tid >> 2, cQ = tid & 3;
  const float* gA32 = AF32 ? (const float*)Av + (size_t)(m0 + cR) * lda + cQ * 16 : nullptr;
  const float* gB32 = BF32 ? (const float*)Bv + (size_t)(n0 + cR) * ldb + cQ * 16 : nullptr;

  f32x4 acc[2][2];
#pragma unroll
  for (int i = 0; i < 2; ++i)
#pragma unroll
    for (int j = 0; j < 2; ++j)
      acc[i][j] = (f32x4){0.f, 0.f, 0.f, 0.f};

  const int wr = wave >> 1, wc = wave & 1;
  const int mW = wr * 32, nW = wc * 32;
  const int fragRow = lane & 15;
  const int quad = lane >> 4;

  float4 la[4], lb[4];                   // in-flight fp32 stage regs

  auto issue = [&](int kt, int buf) {
    if (AF32) {
#pragma unroll
      for (int f = 0; f < 4; ++f) la[f] = *(const float4*)(gA32 + kt + 4 * f);
    } else {
      bf16* dA = As + buf * (64 * 64);
#pragma unroll
      for (int t = 0; t < 2; ++t)
        GLOAD_LDS16(gA16 + (size_t)((t * 4 + wave) * 8) * lda + kt, &dA[(t * 4 + wave) * 8 * 64]);
    }
    if (BF32) {
#pragma unroll
      for (int f = 0; f < 4; ++f) lb[f] = *(const float4*)(gB32 + kt + 4 * f);
    } else {
      bf16* dB = Bs + buf * (64 * 64);
#pragma unroll
      for (int t = 0; t < 2; ++t)
        GLOAD_LDS16(gB16 + (size_t)((t * 4 + wave) * 8) * ldb + kt, &dB[(t * 4 + wave) * 8 * 64]);
    }
  };

  auto commit = [&](int buf) {           // cvt fp32 regs -> LDS (if any)
    if (AF32) {
      bf16* dA = As + buf * (64 * 64);
#pragma unroll
      for (int j = 0; j < 2; ++j) {
        const int sl = (2 * cQ + j) ^ (cR & 7);
        *(bf16x8*)&dA[cR * 64 + sl * 8] = cvt8(la[2 * j], la[2 * j + 1]);
      }
    }
    if (BF32) {
      bf16* dB = Bs + buf * (64 * 64);
#pragma unroll
      for (int j = 0; j < 2; ++j) {
        const int sl = (2 * cQ + j) ^ (cR & 7);
        *(bf16x8*)&dB[cR * 64 + sl * 8] = cvt8(lb[2 * j], lb[2 * j + 1]);
      }
    }
  };

  const int nT = K >> 6;
  issue(0, 0);
  for (int kt = 0; kt < nT; ++kt) {
    const int buf = kt & 1;
    commit(buf);                          // compiler waits fp32 loads precisely
    asm volatile("s_waitcnt vmcnt(0) lgkmcnt(0)" ::: "memory");  // DMA(kt)+writes
    asm volatile("s_barrier" ::: "memory");
    if (kt + 1 < nT) issue((kt + 1) << 6, buf ^ 1);   // readers(kt-1) done

    const bf16* Ab = As + buf * (64 * 64);
    const bf16* Bb = Bs + buf * (64 * 64);
    bf16x8 afr[2][2], bfr[2][2];
#pragma unroll
    for (int s = 0; s < 2; ++s) {
      const int cw = s * 4 + quad;
#pragma unroll
      for (int i = 0; i < 2; ++i) {
        const int ra = mW + i * 16 + fragRow;
        afr[s][i] = *(const bf16x8*)&Ab[ra * 64 + ((cw ^ (ra & 7)) << 3)];
        const int rb = nW + i * 16 + fragRow;
        bfr[s][i] = *(const bf16x8*)&Bb[rb * 64 + ((cw ^ (rb & 7)) << 3)];
      }
    }
    asm volatile("s_waitcnt lgkmcnt(0)" ::: "memory");

#pragma unroll
    for (int s = 0; s < 2; ++s)
#pragma unroll
      for (int i = 0; i < 2; ++i)
#pragma unroll
        for (int j = 0; j < 2; ++j)
          acc[i][j] = __builtin_amdgcn_mfma_f32_16x16x32_bf16(afr[s][i], bfr[s][j], acc[i][j], 0, 0, 0);
  }

  const int cCol  = lane & 15;
  const int cRow4 = quad * 4;
#pragma unroll
  for (int i = 0; i < 2; ++i)
#pragma unroll
    for (int j = 0; j < 2; ++j) {
      const int row = m0 + mW + i * 16 + cRow4;
      const int col = n0 + nW + j * 16 + cCol;
#pragma unroll
      for (int r = 0; r < 4; ++r)
        store_out(&C[(size_t)(row + r) * ldc + col], acc[i][j][r]);
    }
}

// ---------------------------------------------------------------------------
// transpose-cast tile helper: src fp32 [R x 1024] tile (r0,c0) 128x64 ->
// dstT bf16 [1024 x ldT]; optionally dst row-copy bf16.
__device__ __forceinline__ void tcast_tile(
    const float* __restrict__ src, bf16* __restrict__ dst, bf16* __restrict__ dstT,
    int r0, int c0, int ldT, bf16* smem)
{
  bf16 (*t)[68] = (bf16(*)[68])smem;
  const int tid = threadIdx.x;
#pragma unroll
  for (int p = 0; p < 8; ++p) {
    const int q = tid + p * 256;
    const int r = q >> 4, c4 = (q & 15) * 4;
    const float4 f = *(const float4*)&src[(size_t)(r0 + r) * DIN + c0 + c4];
    short4 s4;
    s4.x = bfbits(f.x); s4.y = bfbits(f.y); s4.z = bfbits(f.z); s4.w = bfbits(f.w);
    if (dst) *(short4*)&dst[(size_t)(r0 + r) * DIN + c0 + c4] = s4;
    *(short4*)&t[r][c4] = s4;
  }
  __syncthreads();
#pragma unroll
  for (int p = 0; p < 4; ++p) {
    const int h = tid + p * 256;
    const int c = h >> 4, seg = h & 15;
    bf16x8 o;
#pragma unroll
    for (int i = 0; i < 8; ++i)
      o[i] = *(const short*)&t[seg * 8 + i][c];
    *(bf16x8*)&dstT[(size_t)(c0 + c) * ldT + r0 + seg * 8] = o;
  }
}

// D1: x -> xb + xTb (1024 tiles of 128x64); x read exactly once.
__global__ __launch_bounds__(256) void prep_x(
    const float* __restrict__ x, bf16* __restrict__ xb, bf16* __restrict__ xTb)
{
  __shared__ bf16 sm[128 * 68];
  const int b = blockIdx.x;              // 64 x 16
  tcast_tile(x, xb, xTb, (b >> 4) * 128, (b & 15) * 64, SEQ, sm);
}

// D2: blocks 0..511 G (full, split-K atomic fp32), 512..767 P1 (fp32 cvt),
//     768..895 WV -> WVT transpose.
__global__ __launch_bounds__(256) void g_p1(
    const bf16* __restrict__ xT, const float* __restrict__ WQ,
    const float* __restrict__ WK, const float* __restrict__ WV,
    float* __restrict__ Gf, bf16* __restrict__ P1, bf16* __restrict__ WVTb)
{
  __shared__ bf16 sm[32768];             // 64 KB
  const int b = blockIdx.x;
  if (b < 512) {
    const int z = b & 7;                 // XCD-local K-chunk
    const int r = b >> 3;                // 64 tiles
    const bf16* Az = xT + (size_t)z * 1024;
    gemm128_body<float, true>(Az, Az, Gf, r & 7, r >> 3, 1024, 8192, 8192, 1024,
                              sm, sm + 2 * 128 * 64);
  } else if (b < 768) {
    const int p = b - 512;
    gemm64s_body<true, true, bf16>(WQ, WK, P1, p & 15, p >> 4,
                                   1024, 1024, 1024, 1024,
                                   sm, sm + 2 * 64 * 64);
  } else {
    const int p = b - 768;               // 8 x 16 tiles of WV
    tcast_tile(WV, nullptr, WVTb, (p >> 4) * 128, (p & 15) * 64, DIN, sm);
  }
}

// D3: Ut = WV^T G  (A bf16 DMA, B = fp32 G cvt-staged; G symmetric -> B^T = G)
__global__ __launch_bounds__(256) void ut_k(
    const bf16* __restrict__ WVTb, const float* __restrict__ Gf, bf16* __restrict__ Ut)
{
  __shared__ bf16 sm[4 * 64 * 64];
  gemm64s_body<false, true, bf16>(WVTb, Gf, Ut, blockIdx.x, blockIdx.y,
                                  1024, 1024, 1024, 1024, sm, sm + 2 * 64 * 64);
}

// D4: W'^T = Ut P1^T  (both bf16)
__global__ __launch_bounds__(256) void wp_k(
    const bf16* __restrict__ Ut, const bf16* __restrict__ P1, bf16* __restrict__ WpT)
{
  __shared__ bf16 sm[4 * 64 * 64];
  gemm64s_body<false, false, bf16>(Ut, P1, WpT, blockIdx.x, blockIdx.y,
                                   1024, 1024, 1024, 1024, sm, sm + 2 * 64 * 64);
}

// D5: out = x W'  (XCD-swizzled)
__global__ __launch_bounds__(256) void gemm128_f32(
    const bf16* __restrict__ A, const bf16* __restrict__ B, float* __restrict__ C)
{
  __shared__ bf16 sm[32768];
  const int id = blockIdx.x;
  const int by = ((id & 7) << 3) | ((id >> 3) & 7);
  const int bx = id >> 6;
  gemm128_body<float, false>(A, B, C, bx, by, 1024, 1024, 1024, DOUT,
                             sm, sm + 2 * 128 * 64);
}

// ---------------------------------------------------------------------------
extern "C" void kernel_launch(void* const* d_in, const int* in_sizes, int n_in,
                              void* d_out, int out_size, void* d_ws, size_t ws_size,
                              hipStream_t stream)
{
  const float* x  = (const float*)d_in[0];
  const float* WQ = (const float*)d_in[1];
  const float* WK = (const float*)d_in[2];
  const float* WV = (const float*)d_in[3];
  float* out = (float*)d_out;

  char* ws = (char*)d_ws;
  size_t off = 0;
  auto alloc = [&](size_t bytes) -> void* {
    void* p = ws + off;
    off += (bytes + 255) & ~(size_t)255;
    return p;
  };

  const size_t xBytes = (size_t)SEQ * DIN * sizeof(bf16);
  const size_t wBytes = (size_t)DIN * DOUT * sizeof(bf16);

  bf16*  xb   = (bf16*)alloc(xBytes);            // x, bf16
  bf16*  xTb  = (bf16*)alloc(xBytes);            // x^T, bf16
  bf16*  WVTb = (bf16*)alloc(wBytes);            // WV^T bf16
  float* Gf   = (float*)alloc((size_t)DIN * DOUT * sizeof(float));  // x^T x, fp32
  bf16*  P1b  = (bf16*)alloc(wBytes);            // WQ WK^T
  bf16*  Utb  = (bf16*)alloc(wBytes);            // WV^T G
  bf16*  WpTb = (bf16*)alloc(wBytes);            // W'^T

  hipMemsetAsync(Gf, 0, (size_t)DIN * DOUT * sizeof(float), stream);  // for atomics

  prep_x<<<dim3(1024), 256, 0, stream>>>(x, xb, xTb);
  g_p1<<<dim3(896), 256, 0, stream>>>(xTb, WQ, WK, WV, Gf, P1b, WVTb);
  ut_k<<<dim3(16, 16), 256, 0, stream>>>(WVTb, Gf, Utb);
  wp_k<<<dim3(16, 16), 256, 0, stream>>>(Utb, P1b, WpTb);
  gemm128_f32<<<dim3(512), 256, 0, stream>>>(xb, WpTb, out);
}